// Round 1
// baseline (87.433 us; speedup 1.0000x reference)
//
#include <hip/hip_runtime.h>

#define DD 32
#define M_ROWS 1000
#define EPS 1e-5f

// ---------------- Kernel A: adapter FFN on the 1000 rows ----------------
// f[m] = LayerNorm(x + ReLU(x@aw1+ab1)@aw2 + ab2) * ag + abt
__global__ __launch_bounds__(256) void adapter_ffn_kernel(
    const float* __restrict__ feat,
    const float* __restrict__ aw1, const float* __restrict__ ab1,
    const float* __restrict__ aw2, const float* __restrict__ ab2,
    const float* __restrict__ ag,  const float* __restrict__ abt,
    float* __restrict__ frows)
{
    const int m = blockIdx.x * 256 + threadIdx.x;
    if (m >= M_ROWS) return;
    float x[DD], h[DD], y[DD];
    const float4* xp = reinterpret_cast<const float4*>(feat + m * DD);
#pragma unroll
    for (int q = 0; q < DD / 4; ++q) {
        float4 v = xp[q];
        x[4*q+0] = v.x; x[4*q+1] = v.y; x[4*q+2] = v.z; x[4*q+3] = v.w;
    }
#pragma unroll
    for (int k = 0; k < DD; ++k) h[k] = ab1[k];
#pragma unroll
    for (int d = 0; d < DD; ++d)
#pragma unroll
        for (int k = 0; k < DD; ++k)
            h[k] = fmaf(x[d], aw1[d*DD + k], h[k]);
#pragma unroll
    for (int k = 0; k < DD; ++k) h[k] = fmaxf(h[k], 0.0f);
#pragma unroll
    for (int d = 0; d < DD; ++d) y[d] = x[d] + ab2[d];
#pragma unroll
    for (int k = 0; k < DD; ++k)
#pragma unroll
        for (int d = 0; d < DD; ++d)
            y[d] = fmaf(h[k], aw2[k*DD + d], y[d]);
    float mean = 0.f;
#pragma unroll
    for (int d = 0; d < DD; ++d) mean += y[d];
    mean *= (1.0f / DD);
    float var = 0.f;
#pragma unroll
    for (int d = 0; d < DD; ++d) { float t = y[d] - mean; var = fmaf(t, t, var); }
    var *= (1.0f / DD);
    const float s = rsqrtf(var + EPS);
    float4* op = reinterpret_cast<float4*>(frows + m * DD);
#pragma unroll
    for (int q = 0; q < DD / 4; ++q) {
        float4 v;
        v.x = (y[4*q+0] - mean) * s * ag[4*q+0] + abt[4*q+0];
        v.y = (y[4*q+1] - mean) * s * ag[4*q+1] + abt[4*q+1];
        v.z = (y[4*q+2] - mean) * s * ag[4*q+2] + abt[4*q+2];
        v.w = (y[4*q+3] - mean) * s * ag[4*q+3] + abt[4*q+3];
        op[q] = v;
    }
}

// ---------------- Kernel B: per-pair head ----------------
// out[i*1000+j] = (LN2(FFN(LN1(f_i+f_j))) @ ow + ob) + ddg[i] + ddg[j]
// thread layout: 64 consecutive j per wave (coalesced out-writes), 4 i per block
__global__ __launch_bounds__(256) void pair_head_kernel(
    const float* __restrict__ frows,
    const float* __restrict__ ddg,
    const float* __restrict__ hg,  const float* __restrict__ hbt,
    const float* __restrict__ fw1, const float* __restrict__ fb1,
    const float* __restrict__ fw2, const float* __restrict__ fb2,
    const float* __restrict__ fg,  const float* __restrict__ fbt,
    const float* __restrict__ ow,  const float* __restrict__ ob,
    float* __restrict__ out)
{
    const int tx = threadIdx.x;
    const int j = blockIdx.x * 64 + (tx & 63);
    const int i = blockIdx.y * 4 + (tx >> 6);
    if (j >= M_ROWS) return;

    float u[DD], h[DD], y[DD];
    const float4* fi = reinterpret_cast<const float4*>(frows + i * DD);
    const float4* fj = reinterpret_cast<const float4*>(frows + j * DD);
#pragma unroll
    for (int q = 0; q < DD / 4; ++q) {
        float4 a = fi[q]; float4 b = fj[q];
        u[4*q+0] = a.x + b.x; u[4*q+1] = a.y + b.y;
        u[4*q+2] = a.z + b.z; u[4*q+3] = a.w + b.w;
    }
    // LN1
    float mean = 0.f;
#pragma unroll
    for (int d = 0; d < DD; ++d) mean += u[d];
    mean *= (1.0f / DD);
    float var = 0.f;
#pragma unroll
    for (int d = 0; d < DD; ++d) { float t = u[d] - mean; var = fmaf(t, t, var); }
    var *= (1.0f / DD);
    float s = rsqrtf(var + EPS);
#pragma unroll
    for (int d = 0; d < DD; ++d) u[d] = (u[d] - mean) * s * hg[d] + hbt[d];
    // FFN: h = relu(u @ fw1 + fb1); y = u + h @ fw2 + fb2
#pragma unroll
    for (int k = 0; k < DD; ++k) h[k] = fb1[k];
#pragma unroll
    for (int d = 0; d < DD; ++d)
#pragma unroll
        for (int k = 0; k < DD; ++k)
            h[k] = fmaf(u[d], fw1[d*DD + k], h[k]);
#pragma unroll
    for (int k = 0; k < DD; ++k) h[k] = fmaxf(h[k], 0.0f);
#pragma unroll
    for (int d = 0; d < DD; ++d) y[d] = u[d] + fb2[d];
#pragma unroll
    for (int k = 0; k < DD; ++k)
#pragma unroll
        for (int d = 0; d < DD; ++d)
            y[d] = fmaf(h[k], fw2[k*DD + d], y[d]);
    // LN2 + dot(ow)
    float mean2 = 0.f;
#pragma unroll
    for (int d = 0; d < DD; ++d) mean2 += y[d];
    mean2 *= (1.0f / DD);
    float var2 = 0.f;
#pragma unroll
    for (int d = 0; d < DD; ++d) { float t = y[d] - mean2; var2 = fmaf(t, t, var2); }
    var2 *= (1.0f / DD);
    float s2 = rsqrtf(var2 + EPS);
    float acc = ob[0];
#pragma unroll
    for (int d = 0; d < DD; ++d)
        acc = fmaf((y[d] - mean2) * s2 * fg[d] + fbt[d], ow[d], acc);

    out[i * M_ROWS + j] = acc + ddg[i] + ddg[j];
}

extern "C" void kernel_launch(void* const* d_in, const int* in_sizes, int n_in,
                              void* d_out, int out_size, void* d_ws, size_t ws_size,
                              hipStream_t stream) {
    const float* feat = (const float*)d_in[0];
    const float* ddg  = (const float*)d_in[1];
    const float* aw1  = (const float*)d_in[2];
    const float* ab1  = (const float*)d_in[3];
    const float* aw2  = (const float*)d_in[4];
    const float* ab2  = (const float*)d_in[5];
    const float* ag   = (const float*)d_in[6];
    const float* abt  = (const float*)d_in[7];
    const float* hg   = (const float*)d_in[8];
    const float* hbt  = (const float*)d_in[9];
    const float* fw1  = (const float*)d_in[10];
    const float* fb1  = (const float*)d_in[11];
    const float* fw2  = (const float*)d_in[12];
    const float* fb2  = (const float*)d_in[13];
    const float* fg   = (const float*)d_in[14];
    const float* fbt  = (const float*)d_in[15];
    const float* ow   = (const float*)d_in[16];
    const float* ob   = (const float*)d_in[17];
    float* out   = (float*)d_out;
    float* frows = (float*)d_ws;   // 1000*32*4 = 128 KB scratch

    adapter_ffn_kernel<<<dim3((M_ROWS + 255) / 256), dim3(256), 0, stream>>>(
        feat, aw1, ab1, aw2, ab2, ag, abt, frows);
    pair_head_kernel<<<dim3(16, 250), dim3(256), 0, stream>>>(
        frows, ddg, hg, hbt, fw1, fb1, fw2, fb2, fg, fbt, ow, ob, out);
}

// Round 2
// 66.382 us; speedup vs baseline: 1.3171x; 1.3171x over previous
//
#include <hip/hip_runtime.h>

#define DD 32
#define M_ROWS 1000
#define EPS 1e-5f

// ws layout (floats): fprime @0, fph @32000, g @64000, S @96000, consts @97024
// consts: [0:32)=c, [32:64)=cb, [64:96)=e, [96]=E, [97]=F

// ---------- A1: adapter FFN + center + S + f'*hg ----------
__global__ __launch_bounds__(256) void adapter_fprime_kernel(
    const float* __restrict__ feat,
    const float* __restrict__ aw1, const float* __restrict__ ab1,
    const float* __restrict__ aw2, const float* __restrict__ ab2,
    const float* __restrict__ ag,  const float* __restrict__ abt,
    const float* __restrict__ hg,
    float* __restrict__ fprime, float* __restrict__ fph, float* __restrict__ Srow)
{
    const int m = blockIdx.x * 256 + threadIdx.x;
    if (m >= M_ROWS) return;
    float x[DD], h[DD], y[DD];
    const float4* xp = reinterpret_cast<const float4*>(feat + m * DD);
#pragma unroll
    for (int q = 0; q < DD / 4; ++q) {
        float4 v = xp[q];
        x[4*q+0] = v.x; x[4*q+1] = v.y; x[4*q+2] = v.z; x[4*q+3] = v.w;
    }
#pragma unroll
    for (int k = 0; k < DD; ++k) h[k] = ab1[k];
#pragma unroll
    for (int d = 0; d < DD; ++d)
#pragma unroll
        for (int k = 0; k < DD; ++k)
            h[k] = fmaf(x[d], aw1[d*DD + k], h[k]);
#pragma unroll
    for (int k = 0; k < DD; ++k) h[k] = fmaxf(h[k], 0.0f);
#pragma unroll
    for (int d = 0; d < DD; ++d) y[d] = x[d] + ab2[d];
#pragma unroll
    for (int k = 0; k < DD; ++k)
#pragma unroll
        for (int d = 0; d < DD; ++d)
            y[d] = fmaf(h[k], aw2[k*DD + d], y[d]);
    float mean = 0.f;
#pragma unroll
    for (int d = 0; d < DD; ++d) mean += y[d];
    mean *= (1.0f / DD);
    float var = 0.f;
#pragma unroll
    for (int d = 0; d < DD; ++d) { float t = y[d] - mean; var = fmaf(t, t, var); }
    var *= (1.0f / DD);
    const float s = rsqrtf(var + EPS);
    float f[DD];
#pragma unroll
    for (int d = 0; d < DD; ++d) f[d] = (y[d] - mean) * s * ag[d] + abt[d];
    // center for head LN1
    float fm = 0.f;
#pragma unroll
    for (int d = 0; d < DD; ++d) fm += f[d];
    fm *= (1.0f / DD);
    float S = 0.f;
    float fp[DD];
#pragma unroll
    for (int d = 0; d < DD; ++d) { fp[d] = f[d] - fm; S = fmaf(fp[d], fp[d], S); }
    Srow[m] = S;
    float4* op  = reinterpret_cast<float4*>(fprime + m * DD);
    float4* op2 = reinterpret_cast<float4*>(fph    + m * DD);
#pragma unroll
    for (int q = 0; q < DD / 4; ++q) {
        float4 v; float4 w;
        v.x = fp[4*q+0]; v.y = fp[4*q+1]; v.z = fp[4*q+2]; v.w = fp[4*q+3];
        w.x = v.x * hg[4*q+0]; w.y = v.y * hg[4*q+1];
        w.z = v.z * hg[4*q+2]; w.w = v.w * hg[4*q+3];
        op[q] = v; op2[q] = w;
    }
}

// ---------- A2: g[m][k] = sum_d fph[m][d] * fw1[d][k] ----------
__global__ __launch_bounds__(256) void gmat_kernel(
    const float* __restrict__ fph, const float* __restrict__ fw1,
    float* __restrict__ g)
{
    const int t = blockIdx.x * 256 + threadIdx.x;   // 32000 threads
    const int m = t >> 5;
    const int k = t & 31;
    if (m >= M_ROWS) return;
    float fp[DD];
    const float4* fp4 = reinterpret_cast<const float4*>(fph + m * DD);
#pragma unroll
    for (int q = 0; q < DD / 4; ++q) {
        float4 v = fp4[q];
        fp[4*q+0] = v.x; fp[4*q+1] = v.y; fp[4*q+2] = v.z; fp[4*q+3] = v.w;
    }
    float acc = 0.f;
#pragma unroll
    for (int d = 0; d < DD; ++d) acc = fmaf(fp[d], fw1[d*DD + k], acc);
    g[m*DD + k] = acc;
}

// ---------- prep: fused constant vectors/scalars ----------
__global__ void prep_consts_kernel(
    const float* __restrict__ fw1, const float* __restrict__ fb1,
    const float* __restrict__ hbt, const float* __restrict__ fb2,
    const float* __restrict__ fg,  const float* __restrict__ fbt,
    const float* __restrict__ ow,  const float* __restrict__ ob,
    float* __restrict__ consts)
{
    const int k = threadIdx.x;
    if (k < DD) {
        float c = fb1[k];
#pragma unroll
        for (int d = 0; d < DD; ++d) c = fmaf(hbt[d], fw1[d*DD + k], c);
        consts[k]      = c;                 // c
        consts[32 + k] = hbt[k] + fb2[k];   // cb
        consts[64 + k] = fg[k] * ow[k];     // e
    }
    if (k == 0) {
        float E = 0.f, F = ob[0];
#pragma unroll
        for (int d = 0; d < DD; ++d) { E += fg[d] * ow[d]; F = fmaf(fbt[d], ow[d], F); }
        consts[96] = E; consts[97] = F;
    }
}

// ---------- pair head ----------
__global__ __launch_bounds__(256, 4) void pair_head_kernel(
    const float* __restrict__ fprime, const float* __restrict__ g,
    const float* __restrict__ Srow,   const float* __restrict__ ddg,
    const float* __restrict__ hg,     const float* __restrict__ fw2,
    const float* __restrict__ consts, float* __restrict__ out)
{
    const int tx = threadIdx.x;
    const int i = __builtin_amdgcn_readfirstlane(blockIdx.y * 4 + (tx >> 6));
    const int j = blockIdx.x * 64 + (tx & 63);
    if (j >= M_ROWS) return;

    // j-side (per-lane, coalesced)
    float fj[DD], gj[DD];
    const float4* fj4 = reinterpret_cast<const float4*>(fprime + j * DD);
    const float4* gj4 = reinterpret_cast<const float4*>(g      + j * DD);
#pragma unroll
    for (int q = 0; q < DD / 4; ++q) {
        float4 a = fj4[q];
        fj[4*q+0] = a.x; fj[4*q+1] = a.y; fj[4*q+2] = a.z; fj[4*q+3] = a.w;
    }
#pragma unroll
    for (int q = 0; q < DD / 4; ++q) {
        float4 a = gj4[q];
        gj[4*q+0] = a.x; gj[4*q+1] = a.y; gj[4*q+2] = a.z; gj[4*q+3] = a.w;
    }
    const float Sj = Srow[j];
    const float dj = ddg[j];

    // i-side (wave-uniform -> SGPR)
    const float* __restrict__ fi = fprime + i * DD;
    const float* __restrict__ gi = g      + i * DD;
    const float Si = Srow[i];
    const float di = ddg[i];

    // q = f'_i . f'_j ; p = f'_i + f'_j
    float p[DD];
    float qdot = 0.f;
#pragma unroll
    for (int d = 0; d < DD; ++d) {
        const float a = fi[d];
        qdot = fmaf(a, fj[d], qdot);
        p[d] = a + fj[d];
    }
    const float v1 = (Si + Sj + 2.f * qdot) * (1.0f / DD);
    const float s  = rsqrtf(v1 + EPS);

    // h = relu(s*(g_i+g_j) + c)
    float h[DD];
#pragma unroll
    for (int k = 0; k < DD; ++k)
        h[k] = fmaxf(fmaf(s, gi[k] + gj[k], consts[k]), 0.f);

    // y = s*(p .* hg) + cb + h @ fw2
    float y[DD];
#pragma unroll
    for (int d = 0; d < DD; ++d)
        y[d] = fmaf(s, p[d] * hg[d], consts[32 + d]);
#pragma unroll
    for (int k = 0; k < DD; ++k)
#pragma unroll
        for (int d = 0; d < DD; ++d)
            y[d] = fmaf(h[k], fw2[k*DD + d], y[d]);

    // LN2 folded into dot with ow
    float sy = 0.f, syy = 0.f, sye = 0.f;
#pragma unroll
    for (int d = 0; d < DD; ++d) {
        const float t = y[d];
        sy  += t;
        syy  = fmaf(t, t, syy);
        sye  = fmaf(t, consts[64 + d], sye);
    }
    const float m2   = sy * (1.0f / DD);
    const float var2 = fmaf(-m2, m2, syy * (1.0f / DD));
    const float s2   = rsqrtf(var2 + EPS);
    const float E = consts[96], F = consts[97];

    out[i * M_ROWS + j] = fmaf(s2, fmaf(-m2, E, sye), F) + di + dj;
}

extern "C" void kernel_launch(void* const* d_in, const int* in_sizes, int n_in,
                              void* d_out, int out_size, void* d_ws, size_t ws_size,
                              hipStream_t stream) {
    const float* feat = (const float*)d_in[0];
    const float* ddg  = (const float*)d_in[1];
    const float* aw1  = (const float*)d_in[2];
    const float* ab1  = (const float*)d_in[3];
    const float* aw2  = (const float*)d_in[4];
    const float* ab2  = (const float*)d_in[5];
    const float* ag   = (const float*)d_in[6];
    const float* abt  = (const float*)d_in[7];
    const float* hg   = (const float*)d_in[8];
    const float* hbt  = (const float*)d_in[9];
    const float* fw1  = (const float*)d_in[10];
    const float* fb1  = (const float*)d_in[11];
    const float* fw2  = (const float*)d_in[12];
    const float* fb2  = (const float*)d_in[13];
    const float* fg   = (const float*)d_in[14];
    const float* fbt  = (const float*)d_in[15];
    const float* ow   = (const float*)d_in[16];
    const float* ob   = (const float*)d_in[17];
    float* out = (float*)d_out;

    float* ws      = (float*)d_ws;
    float* fprime  = ws;            // 32000
    float* fph     = ws + 32000;    // 32000
    float* g       = ws + 64000;    // 32000
    float* Srow    = ws + 96000;    // 1000
    float* consts  = ws + 97024;    // 98

    adapter_fprime_kernel<<<dim3((M_ROWS + 255) / 256), dim3(256), 0, stream>>>(
        feat, aw1, ab1, aw2, ab2, ag, abt, hg, fprime, fph, Srow);
    gmat_kernel<<<dim3(125), dim3(256), 0, stream>>>(fph, fw1, g);
    prep_consts_kernel<<<dim3(1), dim3(64), 0, stream>>>(
        fw1, fb1, hbt, fb2, fg, fbt, ow, ob, consts);
    pair_head_kernel<<<dim3(16, 250), dim3(256), 0, stream>>>(
        fprime, g, Srow, ddg, hg, fw2, consts, out);
}